// Round 3
// baseline (596.628 us; speedup 1.0000x reference)
//
#include <hip/hip_runtime.h>
#include <math.h>

// SPP: out = concat([x, maxpool5(x), maxpool9(x), maxpool13(x)], axis=1)
// x: (16, 512, 64, 64) f32 -> out: (16, 2048, 64, 64) f32
//
// One block per (b,c) plane. Separable pooling + pyramid composition:
//   h5 = rowmax5(x); v5 = colmax5(h5)   (= full 5x5 block max)
//   pool9  = max of v5 at (r±2, c±2)            [4 values]
//   pool13 = max of v5 at (r+{-4,0,4}, c+{-4,0,4}) [9 values]
// Borders: -inf pad for the direct rowmax (exact SAME/-inf semantics);
// clamped-index (edge-replicated pad) for the composition step, which is
// provably equivalent to the true clipped window at boundaries.

#define HW 4096  // 64*64

__device__ __forceinline__ float f4c(const float4 v, int j) {
    switch (j & 3) { case 0: return v.x; case 1: return v.y; case 2: return v.z; default: return v.w; }
}
__device__ __forceinline__ void setf4(float4& v, int j, float val) {
    switch (j & 3) { case 0: v.x = val; break; case 1: v.y = val; break; case 2: v.z = val; break; default: v.w = val; }
}
// p in [0,11] over three float4s (compile-time p after unroll -> folds)
#define GET3(a, b, cv, p) ((p) < 4 ? f4c((a), (p)) : ((p) < 8 ? f4c((b), (p) - 4) : f4c((cv), (p) - 8)))

#define STRA 72  // bufA row stride (floats): 64 data + 4 pad each side; 288B rows, 16B-aligned
#define STRB 68  // bufB row stride (floats): 272B rows, 16B-aligned, rotates banks by 4/row

__global__ __launch_bounds__(256, 4) void spp_kernel(const float* __restrict__ x,
                                                     float* __restrict__ out) {
    __shared__ float bufA[64 * STRA];
    __shared__ float bufB[64 * STRB];

    const int t = threadIdx.x;
    const int plane = blockIdx.x;      // 0..8191
    const int b = plane >> 9;
    const int ch = plane & 511;

    const float4* __restrict__ xp = (const float4*)(x + (size_t)plane * HW);
    float* o0 = out + ((size_t)b * 2048 + (size_t)ch) * HW;
    float4* o0v = (float4*)o0;
    float4* o1v = (float4*)(o0 + (size_t)512 * HW);
    float4* o2v = (float4*)(o0 + (size_t)1024 * HW);
    float4* o3v = (float4*)(o0 + (size_t)1536 * HW);

    const float NI = -INFINITY;
    const float4 NI4 = make_float4(NI, NI, NI, NI);

    // ---- P0: load plane -> bufA (with -inf side pads), and write out0 = x ----
    #pragma unroll
    for (int i = 0; i < 4; ++i) {
        const int e4 = i * 256 + t;          // float4 chunk index 0..1023
        const int r = e4 >> 4, k = e4 & 15;  // row, chunk-in-row
        float4 v = xp[e4];
        float4* rowp = (float4*)(bufA + r * STRA + 4);
        rowp[k] = v;
        if (k == 0)  rowp[-1] = NI4;
        if (k == 15) rowp[16] = NI4;
        o0v[e4] = v;
    }
    __syncthreads();

    // ---- P1: h5 = rowmax5(x) -> bufB ----
    #pragma unroll
    for (int i = 0; i < 4; ++i) {
        const int e4 = i * 256 + t;
        const int r = e4 >> 4, k = e4 & 15;
        const float4* rowp = (const float4*)(bufA + r * STRA + 4);
        float4 A = rowp[k - 1], B = rowp[k], C = rowp[k + 1];
        // window cols c-2..c+5 : A.z A.w B.x B.y B.z B.w C.x C.y
        const float x0 = A.z, x1 = A.w, x2 = B.x, x3 = B.y, x4 = B.z, x5 = B.w, x6 = C.x, x7 = C.y;
        const float p0 = fmaxf(x0, x1), p1 = fmaxf(x1, x2), p2 = fmaxf(x2, x3),
                    p3 = fmaxf(x3, x4), p4 = fmaxf(x4, x5), p5 = fmaxf(x5, x6);
        float4 h;
        h.x = fmaxf(fmaxf(p0, p2), x4);
        h.y = fmaxf(fmaxf(p1, p3), x5);
        h.z = fmaxf(fmaxf(p2, p4), x6);
        h.w = fmaxf(fmaxf(p3, p5), x7);
        *(float4*)(bufB + r * STRB + 4 * k) = h;
    }
    __syncthreads();

    // ---- P2: v5 = colmax5(h5) -> bufA (padded, edge-replicated) and out1 ----
    #pragma unroll
    for (int i = 0; i < 4; ++i) {
        const int e4 = i * 256 + t;
        const int r = e4 >> 4, k = e4 & 15;
        const int r0 = max(r - 2, 0), r1 = max(r - 1, 0), r3 = min(r + 1, 63), r4 = min(r + 2, 63);
        const float4 a  = *(const float4*)(bufB + r0 * STRB + 4 * k);
        const float4 bb = *(const float4*)(bufB + r1 * STRB + 4 * k);
        const float4 cc = *(const float4*)(bufB + r  * STRB + 4 * k);
        const float4 d  = *(const float4*)(bufB + r3 * STRB + 4 * k);
        const float4 e  = *(const float4*)(bufB + r4 * STRB + 4 * k);
        float4 m;
        m.x = fmaxf(fmaxf(fmaxf(a.x, bb.x), fmaxf(cc.x, d.x)), e.x);
        m.y = fmaxf(fmaxf(fmaxf(a.y, bb.y), fmaxf(cc.y, d.y)), e.y);
        m.z = fmaxf(fmaxf(fmaxf(a.z, bb.z), fmaxf(cc.z, d.z)), e.z);
        m.w = fmaxf(fmaxf(fmaxf(a.w, bb.w), fmaxf(cc.w, d.w)), e.w);
        float4* rowp = (float4*)(bufA + r * STRA + 4);
        rowp[k] = m;
        if (k == 0)  rowp[-1] = make_float4(m.x, m.x, m.x, m.x);  // cols<0 -> clamp to col 0
        if (k == 15) rowp[16] = make_float4(m.w, m.w, m.w, m.w);  // cols>63 -> clamp to col 63
        o1v[e4] = m;
    }
    __syncthreads();

    // ---- P3: out2 = 9x9 max, out3 = 13x13 max, composed from v5 ----
    #pragma unroll
    for (int i = 0; i < 4; ++i) {
        const int e4 = i * 256 + t;
        const int r = e4 >> 4, k = e4 & 15;
        const int rA = max(r - 4, 0), rB = max(r - 2, 0);
        const int rC = min(r + 2, 63), rD = min(r + 4, 63);
        #define ROWF4(rr) ((const float4*)(bufA + (rr) * STRA + 4))
        const float4 A0 = ROWF4(rA)[k - 1], A1 = ROWF4(rA)[k], A2 = ROWF4(rA)[k + 1];
        const float4 B0 = ROWF4(rB)[k - 1], B1 = ROWF4(rB)[k], B2 = ROWF4(rB)[k + 1];
        const float4 M0 = ROWF4(r)[k - 1],  M1 = ROWF4(r)[k],  M2 = ROWF4(r)[k + 1];
        const float4 C0 = ROWF4(rC)[k - 1], C1 = ROWF4(rC)[k], C2 = ROWF4(rC)[k + 1];
        const float4 D0 = ROWF4(rD)[k - 1], D1 = ROWF4(rD)[k], D2 = ROWF4(rD)[k + 1];
        #undef ROWF4
        float4 o2r, o3r;
        #pragma unroll
        for (int j = 0; j < 4; ++j) {
            // positions within the 12-float window (cols c-4 .. c+7)
            const float v2 = fmaxf(fmaxf(GET3(B0, B1, B2, j + 2), GET3(B0, B1, B2, j + 6)),
                                   fmaxf(GET3(C0, C1, C2, j + 2), GET3(C0, C1, C2, j + 6)));
            const float v3a = fmaxf(fmaxf(GET3(A0, A1, A2, j), GET3(A0, A1, A2, j + 4)),
                                    GET3(A0, A1, A2, j + 8));
            const float v3m = fmaxf(fmaxf(GET3(M0, M1, M2, j), GET3(M0, M1, M2, j + 4)),
                                    GET3(M0, M1, M2, j + 8));
            const float v3d = fmaxf(fmaxf(GET3(D0, D1, D2, j), GET3(D0, D1, D2, j + 4)),
                                    GET3(D0, D1, D2, j + 8));
            setf4(o2r, j, v2);
            setf4(o3r, j, fmaxf(fmaxf(v3a, v3m), v3d));
        }
        o2v[e4] = o2r;
        o3v[e4] = o3r;
    }
}

extern "C" void kernel_launch(void* const* d_in, const int* in_sizes, int n_in,
                              void* d_out, int out_size, void* d_ws, size_t ws_size,
                              hipStream_t stream) {
    const float* x = (const float*)d_in[0];
    float* out = (float*)d_out;
    // 16 * 512 = 8192 planes, one block each
    spp_kernel<<<dim3(8192), dim3(256), 0, stream>>>(x, out);
}

// Round 5
// 595.462 us; speedup vs baseline: 1.0020x; 1.0020x over previous
//
#include <hip/hip_runtime.h>
#include <math.h>

// SPP: out = concat([x, maxpool5(x), maxpool9(x), maxpool13(x)], axis=1)
// x: (16, 512, 64, 64) f32 -> out: (16, 2048, 64, 64) f32
//
// One block per (b,c) plane. Separable pooling + pyramid composition:
//   h5 = rowmax5(x); v5 = colmax5(h5)   (= full 5x5 block max)
//   pool9  = max of v5 at (r±2, c±2)            [4 values]
//   pool13 = max of v5 at (r+{-4,0,4}, c+{-4,0,4}) [9 values]
// Borders: -inf pad for the direct rowmax (exact SAME/-inf semantics);
// clamped-index (edge-replicated pad) for the composition step (provably
// equivalent to the true clipped window at boundaries; verified absmax 0.0 in R3).
//
// R5 = R4 with ext_vector_type(4) float instead of HIP float4 (the
// nontemporal builtins reject HIP_vector_type).
//  - P3 split into P3a (9x9) + P3b (13x13), unroll 2: peak live f32x4 set
//    15 -> 6..9, avoiding VGPR spills under the 128-reg cap of (256,4).
//  - nontemporal loads/stores for all global traffic (read-once/write-once).

#define HW 4096  // 64*64

typedef float f32x4 __attribute__((ext_vector_type(4)));

// p in [0,11] over three f32x4s (compile-time p after unroll -> folds)
#define GET3(a, b, cv, p) ((p) < 4 ? (a)[(p)] : ((p) < 8 ? (b)[(p) - 4] : (cv)[(p) - 8]))

#define STRA 72  // bufA row stride (floats): 64 data + 4 pad each side; 288B rows, 16B-aligned
#define STRB 68  // bufB row stride (floats): 272B rows, 16B-aligned, rotates banks by 4/row

__global__ __launch_bounds__(256, 4) void spp_kernel(const float* __restrict__ x,
                                                     float* __restrict__ out) {
    __shared__ float bufA[64 * STRA];
    __shared__ float bufB[64 * STRB];

    const int t = threadIdx.x;
    const int plane = blockIdx.x;      // 0..8191
    const int b = plane >> 9;
    const int ch = plane & 511;

    const f32x4* __restrict__ xp = (const f32x4*)(x + (size_t)plane * HW);
    float* o0 = out + ((size_t)b * 2048 + (size_t)ch) * HW;
    f32x4* o0v = (f32x4*)o0;
    f32x4* o1v = (f32x4*)(o0 + (size_t)512 * HW);
    f32x4* o2v = (f32x4*)(o0 + (size_t)1024 * HW);
    f32x4* o3v = (f32x4*)(o0 + (size_t)1536 * HW);

    const float NI = -INFINITY;
    const f32x4 NI4 = {NI, NI, NI, NI};

    // ---- P0: load plane -> bufA (with -inf side pads), and write out0 = x ----
    #pragma unroll
    for (int i = 0; i < 4; ++i) {
        const int e4 = i * 256 + t;          // f32x4 chunk index 0..1023
        const int r = e4 >> 4, k = e4 & 15;  // row, chunk-in-row
        f32x4 v = __builtin_nontemporal_load(xp + e4);
        f32x4* rowp = (f32x4*)(bufA + r * STRA + 4);
        rowp[k] = v;
        if (k == 0)  rowp[-1] = NI4;
        if (k == 15) rowp[16] = NI4;
        __builtin_nontemporal_store(v, o0v + e4);
    }
    __syncthreads();

    // ---- P1: h5 = rowmax5(x) -> bufB ----
    #pragma unroll
    for (int i = 0; i < 4; ++i) {
        const int e4 = i * 256 + t;
        const int r = e4 >> 4, k = e4 & 15;
        const f32x4* rowp = (const f32x4*)(bufA + r * STRA + 4);
        f32x4 A = rowp[k - 1], B = rowp[k], C = rowp[k + 1];
        // window cols c-2..c+5 : A.z A.w B.x B.y B.z B.w C.x C.y
        const float x0 = A.z, x1 = A.w, x2 = B.x, x3 = B.y, x4 = B.z, x5 = B.w, x6 = C.x, x7 = C.y;
        const float p0 = fmaxf(x0, x1), p1 = fmaxf(x1, x2), p2 = fmaxf(x2, x3),
                    p3 = fmaxf(x3, x4), p4 = fmaxf(x4, x5), p5 = fmaxf(x5, x6);
        f32x4 h;
        h.x = fmaxf(fmaxf(p0, p2), x4);
        h.y = fmaxf(fmaxf(p1, p3), x5);
        h.z = fmaxf(fmaxf(p2, p4), x6);
        h.w = fmaxf(fmaxf(p3, p5), x7);
        *(f32x4*)(bufB + r * STRB + 4 * k) = h;
    }
    __syncthreads();

    // ---- P2: v5 = colmax5(h5) -> bufA (padded, edge-replicated) and out1 ----
    #pragma unroll
    for (int i = 0; i < 4; ++i) {
        const int e4 = i * 256 + t;
        const int r = e4 >> 4, k = e4 & 15;
        const int r0 = max(r - 2, 0), r1 = max(r - 1, 0), r3 = min(r + 1, 63), r4 = min(r + 2, 63);
        const f32x4 a  = *(const f32x4*)(bufB + r0 * STRB + 4 * k);
        const f32x4 bb = *(const f32x4*)(bufB + r1 * STRB + 4 * k);
        const f32x4 cc = *(const f32x4*)(bufB + r  * STRB + 4 * k);
        const f32x4 d  = *(const f32x4*)(bufB + r3 * STRB + 4 * k);
        const f32x4 e  = *(const f32x4*)(bufB + r4 * STRB + 4 * k);
        f32x4 m;
        m.x = fmaxf(fmaxf(fmaxf(a.x, bb.x), fmaxf(cc.x, d.x)), e.x);
        m.y = fmaxf(fmaxf(fmaxf(a.y, bb.y), fmaxf(cc.y, d.y)), e.y);
        m.z = fmaxf(fmaxf(fmaxf(a.z, bb.z), fmaxf(cc.z, d.z)), e.z);
        m.w = fmaxf(fmaxf(fmaxf(a.w, bb.w), fmaxf(cc.w, d.w)), e.w);
        f32x4* rowp = (f32x4*)(bufA + r * STRA + 4);
        rowp[k] = m;
        if (k == 0)  rowp[-1] = (f32x4){m.x, m.x, m.x, m.x};  // cols<0 -> clamp to col 0
        if (k == 15) rowp[16] = (f32x4){m.w, m.w, m.w, m.w};  // cols>63 -> clamp to col 63
        __builtin_nontemporal_store(m, o1v + e4);
    }
    __syncthreads();

    #define ROWF4(rr) ((const f32x4*)(bufA + (rr) * STRA + 4))

    // ---- P3a: out2 = 9x9 max = union of 5x5 at (r±2, c±2) ----
    #pragma unroll 2
    for (int i = 0; i < 4; ++i) {
        const int e4 = i * 256 + t;
        const int r = e4 >> 4, k = e4 & 15;
        const int rB = max(r - 2, 0), rC = min(r + 2, 63);
        const f32x4 B0 = ROWF4(rB)[k - 1], B1 = ROWF4(rB)[k], B2 = ROWF4(rB)[k + 1];
        const f32x4 C0 = ROWF4(rC)[k - 1], C1 = ROWF4(rC)[k], C2 = ROWF4(rC)[k + 1];
        f32x4 o2r;
        #pragma unroll
        for (int j = 0; j < 4; ++j) {
            // positions within the 12-float window (cols c-4 .. c+7): c±2 -> p=j+2, j+6
            const float v2 = fmaxf(fmaxf(GET3(B0, B1, B2, j + 2), GET3(B0, B1, B2, j + 6)),
                                   fmaxf(GET3(C0, C1, C2, j + 2), GET3(C0, C1, C2, j + 6)));
            o2r[j] = v2;
        }
        __builtin_nontemporal_store(o2r, o2v + e4);
    }

    // ---- P3b: out3 = 13x13 max = union of 5x5 at (r+{-4,0,4}, c+{-4,0,4}) ----
    #pragma unroll 2
    for (int i = 0; i < 4; ++i) {
        const int e4 = i * 256 + t;
        const int r = e4 >> 4, k = e4 & 15;
        const int rA = max(r - 4, 0), rD = min(r + 4, 63);
        const f32x4 A0 = ROWF4(rA)[k - 1], A1 = ROWF4(rA)[k], A2 = ROWF4(rA)[k + 1];
        const f32x4 M0 = ROWF4(r)[k - 1],  M1 = ROWF4(r)[k],  M2 = ROWF4(r)[k + 1];
        const f32x4 D0 = ROWF4(rD)[k - 1], D1 = ROWF4(rD)[k], D2 = ROWF4(rD)[k + 1];
        f32x4 o3r;
        #pragma unroll
        for (int j = 0; j < 4; ++j) {
            // c-4 -> p=j, c -> p=j+4, c+4 -> p=j+8
            const float v3a = fmaxf(fmaxf(GET3(A0, A1, A2, j), GET3(A0, A1, A2, j + 4)),
                                    GET3(A0, A1, A2, j + 8));
            const float v3m = fmaxf(fmaxf(GET3(M0, M1, M2, j), GET3(M0, M1, M2, j + 4)),
                                    GET3(M0, M1, M2, j + 8));
            const float v3d = fmaxf(fmaxf(GET3(D0, D1, D2, j), GET3(D0, D1, D2, j + 4)),
                                    GET3(D0, D1, D2, j + 8));
            o3r[j] = fmaxf(fmaxf(v3a, v3m), v3d);
        }
        __builtin_nontemporal_store(o3r, o3v + e4);
    }
    #undef ROWF4
}

extern "C" void kernel_launch(void* const* d_in, const int* in_sizes, int n_in,
                              void* d_out, int out_size, void* d_ws, size_t ws_size,
                              hipStream_t stream) {
    const float* x = (const float*)d_in[0];
    float* out = (float*)d_out;
    // 16 * 512 = 8192 planes, one block each
    spp_kernel<<<dim3(8192), dim3(256), 0, stream>>>(x, out);
}